// Round 1
// baseline (763.233 us; speedup 1.0000x reference)
//
#include <hip/hip_runtime.h>
#include <hip/hip_bf16.h>

#define NTOK 4096
#define DIN  1024
#define DHID 4096
#define DOUT 1024
#define NEXP 8
#define TMAX 72   // max 128-row tiles: 8192/128 + 7 partials = 71, +1 slack

typedef __hip_bfloat16 bf16;
typedef short short8 __attribute__((ext_vector_type(8)));
typedef float floatx4 __attribute__((ext_vector_type(4)));

// ---- workspace layout (bytes) ----
#define WS_XB    0ull           // x bf16            [4096*1024]   8.4 MB
#define WS_W1T   8388608ull     // W1^T bf16         [8][4096][1024] 67.1 MB
#define WS_W2T   75497472ull    // W2^T bf16         [8][1024][4096] 67.1 MB
#define WS_H     142606336ull   // h bf16            [8192][4096]  67.1 MB
#define WS_META  209715200ull
// meta region offsets
#define MO_CNT    0     // int[8]
#define MO_OFF    64    // int[8]
#define MO_TILE_E 128   // int[96]
#define MO_TILE_S 512   // int[96]
#define MO_TILE_R 896   // int[96]
#define MO_NT     1280  // int[1]
#define MO_T2I    1536  // int[4096*2]
#define MO_T2W    34304 // float[4096*2]
#define MO_ROWS   67072 // int[8192]
#define MO_ROWW   99840 // float[8192]

// ---------------- cast x: fp32 -> bf16 ----------------
__global__ void k_cast_x(const float* __restrict__ in, bf16* __restrict__ out) {
  int i = (blockIdx.x * 256 + threadIdx.x) * 8;
  float4 a = *(const float4*)(in + i);
  float4 b = *(const float4*)(in + i + 4);
  union { int4 v; bf16 h[8]; } u;
  u.h[0] = __float2bfloat16(a.x); u.h[1] = __float2bfloat16(a.y);
  u.h[2] = __float2bfloat16(a.z); u.h[3] = __float2bfloat16(a.w);
  u.h[4] = __float2bfloat16(b.x); u.h[5] = __float2bfloat16(b.y);
  u.h[6] = __float2bfloat16(b.z); u.h[7] = __float2bfloat16(b.w);
  *(int4*)(out + i) = u.v;
}

// ------- transpose+cast: [R][C] fp32 -> [C][R] bf16, per expert (z) -------
__global__ void k_transpose_cast(const float* __restrict__ in, bf16* __restrict__ out,
                                 int R, int C) {
  __shared__ float t[32][33];
  size_t ebase = (size_t)blockIdx.z * R * C;
  int c0 = blockIdx.x * 32, r0 = blockIdx.y * 32;
  int tx = threadIdx.x, ty = threadIdx.y;  // (32, 8)
  #pragma unroll
  for (int i = 0; i < 32; i += 8)
    t[ty + i][tx] = in[ebase + (size_t)(r0 + ty + i) * C + c0 + tx];
  __syncthreads();
  #pragma unroll
  for (int i = 0; i < 32; i += 8)
    out[ebase + (size_t)(c0 + ty + i) * R + r0 + tx] = __float2bfloat16(t[tx][ty + i]);
}

// ---------------- gating: softmax -> top2 -> softmax(top2 probs) ----------------
__global__ void k_gate(const float* __restrict__ x, const float* __restrict__ Wg,
                       const float* __restrict__ bg, int* __restrict__ t2i,
                       float* __restrict__ t2w, int* __restrict__ cnt) {
  int wave = threadIdx.x >> 6, lane = threadIdx.x & 63;
  int t = blockIdx.x * 4 + wave;
  const float* xr = x + (size_t)t * DIN;
  float acc[8] = {0.f, 0.f, 0.f, 0.f, 0.f, 0.f, 0.f, 0.f};
  for (int d = lane; d < DIN; d += 64) {
    float xv = xr[d];
    const float* wr = Wg + d * 8;
    float4 w0 = *(const float4*)wr;
    float4 w1 = *(const float4*)(wr + 4);
    acc[0] += xv * w0.x; acc[1] += xv * w0.y; acc[2] += xv * w0.z; acc[3] += xv * w0.w;
    acc[4] += xv * w1.x; acc[5] += xv * w1.y; acc[6] += xv * w1.z; acc[7] += xv * w1.w;
  }
  #pragma unroll
  for (int off = 32; off; off >>= 1) {
    #pragma unroll
    for (int e = 0; e < 8; e++) acc[e] += __shfl_xor(acc[e], off, 64);
  }
  if (lane == 0) {
    float p[8], m = -1e30f, s = 0.f;
    #pragma unroll
    for (int e = 0; e < 8; e++) { p[e] = acc[e] + bg[e]; m = fmaxf(m, p[e]); }
    #pragma unroll
    for (int e = 0; e < 8; e++) { p[e] = expf(p[e] - m); s += p[e]; }
    float inv = 1.f / s;
    #pragma unroll
    for (int e = 0; e < 8; e++) p[e] *= inv;
    int i0 = 0;
    #pragma unroll
    for (int e = 1; e < 8; e++) if (p[e] > p[i0]) i0 = e;   // ties -> lowest idx
    int i1 = (i0 == 0) ? 1 : 0;
    #pragma unroll
    for (int e = 0; e < 8; e++) if (e != i0 && p[e] > p[i1]) i1 = e;
    float d = expf(p[i1] - p[i0]);           // softmax over the two PROBABILITIES
    float w0 = 1.f / (1.f + d), w1 = d / (1.f + d);
    t2i[2 * t] = i0; t2i[2 * t + 1] = i1;
    t2w[2 * t] = w0; t2w[2 * t + 1] = w1;
    atomicAdd(&cnt[i0], 1);
    atomicAdd(&cnt[i1], 1);
  }
}

// ---------------- routing: scan + tile map + scatter ----------------
__global__ void k_route(const int* __restrict__ t2i, const float* __restrict__ t2w,
                        const int* __restrict__ cnt, int* __restrict__ off,
                        int* __restrict__ tile_e, int* __restrict__ tile_s,
                        int* __restrict__ tile_r, int* __restrict__ nt,
                        int* __restrict__ rows, float* __restrict__ roww) {
  __shared__ int cur[8];
  if (threadIdx.x == 0) {
    int o = 0, n = 0;
    for (int e = 0; e < 8; e++) {
      off[e] = o; cur[e] = o;
      int c = cnt[e];
      for (int r = 0; r < c; r += 128) {
        tile_e[n] = e; tile_s[n] = o + r; tile_r[n] = min(128, c - r); n++;
      }
      o += c;
    }
    *nt = n;
  }
  __syncthreads();
  for (int t = threadIdx.x; t < NTOK; t += 256) {
    #pragma unroll
    for (int k = 0; k < 2; k++) {
      int e = t2i[2 * t + k];
      int pos = atomicAdd(&cur[e], 1);
      rows[pos] = t;
      roww[pos] = t2w[2 * t + k];
    }
  }
}

// ---------------- grouped GEMM, 128x128 tile, BK=32, 4 waves ----------------
// MODE 1: h = relu(x_gathered @ W1T^T + b1), bf16 out
// MODE 2: out[token] += w * (h @ W2T^T + b2), fp32 atomic
template <int MODE>
__global__ __launch_bounds__(256)
void k_gemm(const bf16* __restrict__ A, const bf16* __restrict__ Bt,
            const float* __restrict__ bias,
            const int* __restrict__ tile_e, const int* __restrict__ tile_s,
            const int* __restrict__ tile_r, const int* __restrict__ nt,
            const int* __restrict__ rows, const float* __restrict__ roww,
            bf16* __restrict__ hout, float* __restrict__ out,
            int K, int N) {
  int tile = blockIdx.x;
  if (tile >= *nt) return;
  int e = tile_e[tile], start = tile_s[tile], mrows = tile_r[tile];
  int n0 = blockIdx.y * 128;
  int tid = threadIdx.x, lane = tid & 63, wave = tid >> 6;
  int wm = wave & 1, wn = wave >> 1;

  // padded LDS: row stride 40 elems (80 B) -> 8-row period covers all 32 banks
  __shared__ bf16 Al[128 * 40];
  __shared__ bf16 Bl[128 * 40];

  int r0 = tid >> 2, r1 = 64 + (tid >> 2), kc = tid & 3;
  int er0 = r0 < mrows ? r0 : 0;
  int er1 = r1 < mrows ? r1 : 0;
  size_t ga0, ga1;
  if (MODE == 1) {
    ga0 = (size_t)rows[start + er0] * K;
    ga1 = (size_t)rows[start + er1] * K;
  } else {
    ga0 = (size_t)(start + er0) * K;
    ga1 = (size_t)(start + er1) * K;
  }
  const bf16* ap0 = A + ga0 + kc * 8;
  const bf16* ap1 = A + ga1 + kc * 8;
  const bf16* bb = Bt + (size_t)e * (DIN * DHID) + (size_t)n0 * K;
  const bf16* bp0 = bb + (size_t)r0 * K + kc * 8;
  const bf16* bp1 = bb + (size_t)r1 * K + kc * 8;

  floatx4 zz = {0.f, 0.f, 0.f, 0.f};
  floatx4 acc[4][4];
  #pragma unroll
  for (int i = 0; i < 4; i++)
    #pragma unroll
    for (int j = 0; j < 4; j++) acc[i][j] = zz;

  int fr = lane & 15, ko = (lane >> 4) * 8;

  for (int k0 = 0; k0 < K; k0 += 32) {
    int4 av0 = *(const int4*)(ap0 + k0);
    int4 av1 = *(const int4*)(ap1 + k0);
    int4 bv0 = *(const int4*)(bp0 + k0);
    int4 bv1 = *(const int4*)(bp1 + k0);
    __syncthreads();
    *(int4*)&Al[r0 * 40 + kc * 8] = av0;
    *(int4*)&Al[r1 * 40 + kc * 8] = av1;
    *(int4*)&Bl[r0 * 40 + kc * 8] = bv0;
    *(int4*)&Bl[r1 * 40 + kc * 8] = bv1;
    __syncthreads();
    short8 af[4], bfr[4];
    #pragma unroll
    for (int i = 0; i < 4; i++)
      af[i] = *(const short8*)&Al[(wm * 64 + i * 16 + fr) * 40 + ko];
    #pragma unroll
    for (int j = 0; j < 4; j++)
      bfr[j] = *(const short8*)&Bl[(wn * 64 + j * 16 + fr) * 40 + ko];
    #pragma unroll
    for (int i = 0; i < 4; i++)
      #pragma unroll
      for (int j = 0; j < 4; j++)
        acc[i][j] = __builtin_amdgcn_mfma_f32_16x16x32_bf16(af[i], bfr[j], acc[i][j], 0, 0, 0);
  }

  // epilogue: C/D layout col=lane&15, row=(lane>>4)*4+reg
  int col_l = lane & 15, quad = lane >> 4;
  if (MODE == 1) {
    #pragma unroll
    for (int i = 0; i < 4; i++) {
      #pragma unroll
      for (int r = 0; r < 4; r++) {
        int row = wm * 64 + i * 16 + quad * 4 + r;
        if (row < mrows) {
          size_t rb = (size_t)(start + row) * N;
          #pragma unroll
          for (int j = 0; j < 4; j++) {
            int col = n0 + wn * 64 + j * 16 + col_l;
            float v = acc[i][j][r] + bias[e * N + col];
            hout[rb + col] = __float2bfloat16(fmaxf(v, 0.f));
          }
        }
      }
    }
  } else {
    #pragma unroll
    for (int i = 0; i < 4; i++) {
      #pragma unroll
      for (int r = 0; r < 4; r++) {
        int row = wm * 64 + i * 16 + quad * 4 + r;
        if (row < mrows) {
          int tok = rows[start + row];
          float w = roww[start + row];
          size_t ob = (size_t)tok * N;
          #pragma unroll
          for (int j = 0; j < 4; j++) {
            int col = n0 + wn * 64 + j * 16 + col_l;
            float v = (acc[i][j][r] + bias[e * N + col]) * w;
            unsafeAtomicAdd(&out[ob + col], v);
          }
        }
      }
    }
  }
}

extern "C" void kernel_launch(void* const* d_in, const int* in_sizes, int n_in,
                              void* d_out, int out_size, void* d_ws, size_t ws_size,
                              hipStream_t stream) {
  const float* x  = (const float*)d_in[0];
  const float* W1 = (const float*)d_in[1];
  const float* b1 = (const float*)d_in[2];
  const float* W2 = (const float*)d_in[3];
  const float* b2 = (const float*)d_in[4];
  const float* Wg = (const float*)d_in[5];
  const float* bg = (const float*)d_in[6];
  float* out = (float*)d_out;
  char* ws = (char*)d_ws;

  bf16* xb  = (bf16*)(ws + WS_XB);
  bf16* w1t = (bf16*)(ws + WS_W1T);
  bf16* w2t = (bf16*)(ws + WS_W2T);
  bf16* h   = (bf16*)(ws + WS_H);
  char* meta = ws + WS_META;
  int*   cnt    = (int*)(meta + MO_CNT);
  int*   off    = (int*)(meta + MO_OFF);
  int*   tile_e = (int*)(meta + MO_TILE_E);
  int*   tile_s = (int*)(meta + MO_TILE_S);
  int*   tile_r = (int*)(meta + MO_TILE_R);
  int*   nt     = (int*)(meta + MO_NT);
  int*   t2i    = (int*)(meta + MO_T2I);
  float* t2w    = (float*)(meta + MO_T2W);
  int*   rows   = (int*)(meta + MO_ROWS);
  float* roww   = (float*)(meta + MO_ROWW);

  hipMemsetAsync(cnt, 0, 64, stream);
  hipMemsetAsync(d_out, 0, (size_t)out_size * sizeof(float), stream);

  k_cast_x<<<(NTOK * DIN) / (256 * 8), 256, 0, stream>>>(x, xb);
  k_transpose_cast<<<dim3(DHID / 32, DIN / 32, NEXP), dim3(32, 8), 0, stream>>>(W1, w1t, DIN, DHID);
  k_transpose_cast<<<dim3(DOUT / 32, DHID / 32, NEXP), dim3(32, 8), 0, stream>>>(W2, w2t, DHID, DOUT);
  k_gate<<<NTOK / 4, 256, 0, stream>>>(x, Wg, bg, t2i, t2w, cnt);
  k_route<<<1, 256, 0, stream>>>(t2i, t2w, cnt, off, tile_e, tile_s, tile_r, nt, rows, roww);
  k_gemm<1><<<dim3(TMAX, DHID / 128), 256, 0, stream>>>(
      xb, w1t, b1, tile_e, tile_s, tile_r, nt, rows, roww, h, nullptr, DIN, DHID);
  k_gemm<2><<<dim3(TMAX, DOUT / 128), 256, 0, stream>>>(
      h, w2t, b2, tile_e, tile_s, tile_r, nt, rows, roww, nullptr, out, DHID, DOUT);
}

// Round 2
// 743.422 us; speedup vs baseline: 1.0266x; 1.0266x over previous
//
#include <hip/hip_runtime.h>
#include <hip/hip_bf16.h>

#define NTOK 4096
#define DIN  1024
#define DHID 4096
#define DOUT 1024
#define NEXP 8
#define TMAX 72   // max 128-row tiles: 8192/128 + 7 partials = 71, +1 slack

typedef __hip_bfloat16 bf16;
typedef short short8 __attribute__((ext_vector_type(8)));
typedef float floatx4 __attribute__((ext_vector_type(4)));

// ---- workspace layout (bytes) ----
#define WS_XB    0ull           // x bf16            [4096*1024]   8.4 MB
#define WS_W1T   8388608ull     // W1^T bf16         [8][4096][1024] 67.1 MB
#define WS_W2T   75497472ull    // W2^T bf16         [8][1024][4096] 67.1 MB
#define WS_H     142606336ull   // h bf16            [8192][4096]  67.1 MB
#define WS_META  209715200ull
// meta region offsets
#define MO_CNT    0     // int[8]
#define MO_OFF    64    // int[8]
#define MO_TILE_E 128   // int[96]
#define MO_TILE_S 512   // int[96]
#define MO_TILE_R 896   // int[96]
#define MO_NT     1280  // int[1]
#define MO_T2I    1536  // int[4096*2]
#define MO_T2W    34304 // float[4096*2]
#define MO_ROWS   67072 // int[8192]
#define MO_ROWW   99840 // float[8192]

// async global->LDS, 16 B per lane; LDS dest must be wave-uniform base + lane*16
__device__ __forceinline__ void gload16(const bf16* g, bf16* l) {
  __builtin_amdgcn_global_load_lds(
      (const __attribute__((address_space(1))) void*)g,
      (__attribute__((address_space(3))) void*)l, 16, 0, 0);
}

// ---------------- cast x: fp32 -> bf16 ----------------
__global__ void k_cast_x(const float* __restrict__ in, bf16* __restrict__ out) {
  int i = (blockIdx.x * 256 + threadIdx.x) * 8;
  float4 a = *(const float4*)(in + i);
  float4 b = *(const float4*)(in + i + 4);
  union { int4 v; bf16 h[8]; } u;
  u.h[0] = __float2bfloat16(a.x); u.h[1] = __float2bfloat16(a.y);
  u.h[2] = __float2bfloat16(a.z); u.h[3] = __float2bfloat16(a.w);
  u.h[4] = __float2bfloat16(b.x); u.h[5] = __float2bfloat16(b.y);
  u.h[6] = __float2bfloat16(b.z); u.h[7] = __float2bfloat16(b.w);
  *(int4*)(out + i) = u.v;
}

// ------- transpose+cast: [R][C] fp32 -> [C][R] bf16, per expert (z) -------
// 64x64 tile, 256 threads. LDS t[c][r] stride 65 (odd mod 32 -> 2-way, free).
__global__ void k_transpose_cast(const float* __restrict__ in, bf16* __restrict__ out,
                                 int R, int C) {
  __shared__ float t[64][65];
  size_t ebase = (size_t)blockIdx.z * R * C;
  int c0 = blockIdx.x * 64, r0 = blockIdx.y * 64;
  int tid = threadIdx.x;
  int rr = tid >> 4;            // 0..15
  int cq = (tid & 15) * 4;      // 0,4,...,60
  #pragma unroll
  for (int i = 0; i < 4; i++) {
    int r = rr + i * 16;
    float4 v = *(const float4*)(in + ebase + (size_t)(r0 + r) * C + c0 + cq);
    t[cq + 0][r] = v.x; t[cq + 1][r] = v.y; t[cq + 2][r] = v.z; t[cq + 3][r] = v.w;
  }
  __syncthreads();
  int cc = tid >> 4;            // 0..15
  int rq = (tid & 15) * 4;      // 0,4,...,60
  #pragma unroll
  for (int i = 0; i < 4; i++) {
    int c = cc + i * 16;
    union { unsigned long long v; bf16 h[4]; } u;
    u.h[0] = __float2bfloat16(t[c][rq + 0]);
    u.h[1] = __float2bfloat16(t[c][rq + 1]);
    u.h[2] = __float2bfloat16(t[c][rq + 2]);
    u.h[3] = __float2bfloat16(t[c][rq + 3]);
    *(unsigned long long*)(out + ebase + (size_t)(c0 + c) * R + r0 + rq) = u.v;
  }
}

// ---------------- gating: softmax -> top2 -> softmax(top2 probs) ----------------
__global__ void k_gate(const float* __restrict__ x, const float* __restrict__ Wg,
                       const float* __restrict__ bg, int* __restrict__ t2i,
                       float* __restrict__ t2w, int* __restrict__ cnt) {
  int wave = threadIdx.x >> 6, lane = threadIdx.x & 63;
  int t = blockIdx.x * 4 + wave;
  const float* xr = x + (size_t)t * DIN;
  float acc[8] = {0.f, 0.f, 0.f, 0.f, 0.f, 0.f, 0.f, 0.f};
  for (int d = lane; d < DIN; d += 64) {
    float xv = xr[d];
    const float* wr = Wg + d * 8;
    float4 w0 = *(const float4*)wr;
    float4 w1 = *(const float4*)(wr + 4);
    acc[0] += xv * w0.x; acc[1] += xv * w0.y; acc[2] += xv * w0.z; acc[3] += xv * w0.w;
    acc[4] += xv * w1.x; acc[5] += xv * w1.y; acc[6] += xv * w1.z; acc[7] += xv * w1.w;
  }
  #pragma unroll
  for (int off = 32; off; off >>= 1) {
    #pragma unroll
    for (int e = 0; e < 8; e++) acc[e] += __shfl_xor(acc[e], off, 64);
  }
  if (lane == 0) {
    float p[8], m = -1e30f, s = 0.f;
    #pragma unroll
    for (int e = 0; e < 8; e++) { p[e] = acc[e] + bg[e]; m = fmaxf(m, p[e]); }
    #pragma unroll
    for (int e = 0; e < 8; e++) { p[e] = expf(p[e] - m); s += p[e]; }
    float inv = 1.f / s;
    #pragma unroll
    for (int e = 0; e < 8; e++) p[e] *= inv;
    int i0 = 0;
    #pragma unroll
    for (int e = 1; e < 8; e++) if (p[e] > p[i0]) i0 = e;   // ties -> lowest idx
    int i1 = (i0 == 0) ? 1 : 0;
    #pragma unroll
    for (int e = 0; e < 8; e++) if (e != i0 && p[e] > p[i1]) i1 = e;
    float d = expf(p[i1] - p[i0]);           // softmax over the two PROBABILITIES
    float w0 = 1.f / (1.f + d), w1 = d / (1.f + d);
    t2i[2 * t] = i0; t2i[2 * t + 1] = i1;
    t2w[2 * t] = w0; t2w[2 * t + 1] = w1;
    atomicAdd(&cnt[i0], 1);
    atomicAdd(&cnt[i1], 1);
  }
}

// ---------------- routing: scan + tile map + scatter ----------------
__global__ void k_route(const int* __restrict__ t2i, const float* __restrict__ t2w,
                        const int* __restrict__ cnt, int* __restrict__ off,
                        int* __restrict__ tile_e, int* __restrict__ tile_s,
                        int* __restrict__ tile_r, int* __restrict__ nt,
                        int* __restrict__ rows, float* __restrict__ roww) {
  __shared__ int cur[8];
  if (threadIdx.x == 0) {
    int o = 0, n = 0;
    for (int e = 0; e < 8; e++) {
      off[e] = o; cur[e] = o;
      int c = cnt[e];
      for (int r = 0; r < c; r += 128) {
        tile_e[n] = e; tile_s[n] = o + r; tile_r[n] = min(128, c - r); n++;
      }
      o += c;
    }
    *nt = n;
  }
  __syncthreads();
  for (int t = threadIdx.x; t < NTOK; t += 256) {
    #pragma unroll
    for (int k = 0; k < 2; k++) {
      int e = t2i[2 * t + k];
      int pos = atomicAdd(&cur[e], 1);
      rows[pos] = t;
      roww[pos] = t2w[2 * t + k];
    }
  }
}

// ---- grouped GEMM, 128x128 tile, BK=32, 4 waves, async global->LDS ----
// MODE 1: h = relu(x_gathered @ W1T^T + b1), bf16 out
// MODE 2: out[token] += w * (h @ W2T^T + b2), fp32 atomic
template <int MODE>
__global__ __launch_bounds__(256)
void k_gemm(const bf16* __restrict__ A, const bf16* __restrict__ Bt,
            const float* __restrict__ bias,
            const int* __restrict__ tile_e, const int* __restrict__ tile_s,
            const int* __restrict__ tile_r, const int* __restrict__ nt,
            const int* __restrict__ rows, const float* __restrict__ roww,
            bf16* __restrict__ hout, float* __restrict__ out,
            int K, int N) {
  int tile = blockIdx.x;
  if (tile >= *nt) return;
  int e = tile_e[tile], start = tile_s[tile], mrows = tile_r[tile];
  int n0 = blockIdx.y * 128;
  int tid = threadIdx.x, lane = tid & 63, wave = tid >> 6;
  int wm = wave & 1, wn = wave >> 1;

  // unpadded LDS: [128 rows][32 k] bf16 = 8 KB each (global_load_lds needs
  // dest == wave-uniform base + lane*16, so inner dim must be contiguous)
  __shared__ bf16 Al[128 * 32];
  __shared__ bf16 Bl[128 * 32];

  int srow = tid >> 2;          // 0..63
  int kc8  = (tid & 3) * 8;     // k elem offset
  int ra0 = srow, ra1 = 64 + srow;
  int er0 = ra0 < mrows ? ra0 : 0;
  int er1 = ra1 < mrows ? ra1 : 0;
  size_t ga0, ga1;
  if (MODE == 1) {
    ga0 = (size_t)rows[start + er0] * K;
    ga1 = (size_t)rows[start + er1] * K;
  } else {
    ga0 = (size_t)(start + er0) * K;
    ga1 = (size_t)(start + er1) * K;
  }
  const bf16* ap0 = A + ga0 + kc8;
  const bf16* ap1 = A + ga1 + kc8;
  const bf16* bb = Bt + (size_t)e * K * N + (size_t)n0 * K;
  const bf16* bp0 = bb + (size_t)srow * K + kc8;
  const bf16* bp1 = bb + (size_t)(64 + srow) * K + kc8;
  // LDS dest: thread tid covers tile bytes [tid*16, tid*16+16) per pass
  bf16* lA0 = Al + tid * 8;
  bf16* lA1 = Al + 2048 + tid * 8;
  bf16* lB0 = Bl + tid * 8;
  bf16* lB1 = Bl + 2048 + tid * 8;

  floatx4 zz = {0.f, 0.f, 0.f, 0.f};
  floatx4 acc[4][4];
  #pragma unroll
  for (int i = 0; i < 4; i++)
    #pragma unroll
    for (int j = 0; j < 4; j++) acc[i][j] = zz;

  int fr = lane & 15, ko = (lane >> 4) * 8;

  for (int k0 = 0; k0 < K; k0 += 32) {
    __syncthreads();                 // previous iter's LDS reads complete
    gload16(ap0 + k0, lA0);
    gload16(ap1 + k0, lA1);
    gload16(bp0 + k0, lB0);
    gload16(bp1 + k0, lB1);
    __syncthreads();                 // drains vmcnt -> LDS tiles ready
    short8 af[4], bfr[4];
    #pragma unroll
    for (int i = 0; i < 4; i++)
      af[i] = *(const short8*)&Al[(wm * 64 + i * 16 + fr) * 32 + ko];
    #pragma unroll
    for (int j = 0; j < 4; j++)
      bfr[j] = *(const short8*)&Bl[(wn * 64 + j * 16 + fr) * 32 + ko];
    #pragma unroll
    for (int i = 0; i < 4; i++)
      #pragma unroll
      for (int j = 0; j < 4; j++)
        acc[i][j] = __builtin_amdgcn_mfma_f32_16x16x32_bf16(af[i], bfr[j], acc[i][j], 0, 0, 0);
  }

  // epilogue: C/D layout col=lane&15, row=(lane>>4)*4+reg
  int col_l = lane & 15, quad = lane >> 4;
  if (MODE == 1) {
    #pragma unroll
    for (int i = 0; i < 4; i++) {
      #pragma unroll
      for (int r = 0; r < 4; r++) {
        int row = wm * 64 + i * 16 + quad * 4 + r;
        if (row < mrows) {
          size_t rb = (size_t)(start + row) * N;
          #pragma unroll
          for (int j = 0; j < 4; j++) {
            int col = n0 + wn * 64 + j * 16 + col_l;
            float v = acc[i][j][r] + bias[e * N + col];
            hout[rb + col] = __float2bfloat16(fmaxf(v, 0.f));
          }
        }
      }
    }
  } else {
    #pragma unroll
    for (int i = 0; i < 4; i++) {
      #pragma unroll
      for (int r = 0; r < 4; r++) {
        int row = wm * 64 + i * 16 + quad * 4 + r;
        if (row < mrows) {
          int tok = rows[start + row];
          float w = roww[start + row];
          size_t ob = (size_t)tok * N;
          #pragma unroll
          for (int j = 0; j < 4; j++) {
            int col = n0 + wn * 64 + j * 16 + col_l;
            float v = (acc[i][j][r] + bias[e * N + col]) * w;
            unsafeAtomicAdd(&out[ob + col], v);
          }
        }
      }
    }
  }
}

extern "C" void kernel_launch(void* const* d_in, const int* in_sizes, int n_in,
                              void* d_out, int out_size, void* d_ws, size_t ws_size,
                              hipStream_t stream) {
  const float* x  = (const float*)d_in[0];
  const float* W1 = (const float*)d_in[1];
  const float* b1 = (const float*)d_in[2];
  const float* W2 = (const float*)d_in[3];
  const float* b2 = (const float*)d_in[4];
  const float* Wg = (const float*)d_in[5];
  const float* bg = (const float*)d_in[6];
  float* out = (float*)d_out;
  char* ws = (char*)d_ws;

  bf16* xb  = (bf16*)(ws + WS_XB);
  bf16* w1t = (bf16*)(ws + WS_W1T);
  bf16* w2t = (bf16*)(ws + WS_W2T);
  bf16* h   = (bf16*)(ws + WS_H);
  char* meta = ws + WS_META;
  int*   cnt    = (int*)(meta + MO_CNT);
  int*   off    = (int*)(meta + MO_OFF);
  int*   tile_e = (int*)(meta + MO_TILE_E);
  int*   tile_s = (int*)(meta + MO_TILE_S);
  int*   tile_r = (int*)(meta + MO_TILE_R);
  int*   nt     = (int*)(meta + MO_NT);
  int*   t2i    = (int*)(meta + MO_T2I);
  float* t2w    = (float*)(meta + MO_T2W);
  int*   rows   = (int*)(meta + MO_ROWS);
  float* roww   = (float*)(meta + MO_ROWW);

  hipMemsetAsync(cnt, 0, 64, stream);
  hipMemsetAsync(d_out, 0, (size_t)out_size * sizeof(float), stream);

  k_cast_x<<<(NTOK * DIN) / (256 * 8), 256, 0, stream>>>(x, xb);
  k_transpose_cast<<<dim3(DHID / 64, DIN / 64, NEXP), 256, 0, stream>>>(W1, w1t, DIN, DHID);
  k_transpose_cast<<<dim3(DOUT / 64, DHID / 64, NEXP), 256, 0, stream>>>(W2, w2t, DHID, DOUT);
  k_gate<<<NTOK / 4, 256, 0, stream>>>(x, Wg, bg, t2i, t2w, cnt);
  k_route<<<1, 256, 0, stream>>>(t2i, t2w, cnt, off, tile_e, tile_s, tile_r, nt, rows, roww);
  k_gemm<1><<<dim3(TMAX, DHID / 128), 256, 0, stream>>>(
      xb, w1t, b1, tile_e, tile_s, tile_r, nt, rows, roww, h, nullptr, DIN, DHID);
  k_gemm<2><<<dim3(TMAX, DOUT / 128), 256, 0, stream>>>(
      h, w2t, b2, tile_e, tile_s, tile_r, nt, rows, roww, nullptr, out, DHID, DOUT);
}

// Round 3
// 703.002 us; speedup vs baseline: 1.0857x; 1.0575x over previous
//
#include <hip/hip_runtime.h>
#include <hip/hip_bf16.h>

#define NTOK 4096
#define DIN  1024
#define DHID 4096
#define DOUT 1024
#define NEXP 8
#define TMAX 72   // max 128-row tiles: 8192/128 + 7 partials = 71, +1 slack

typedef __hip_bfloat16 bf16;
typedef short short8 __attribute__((ext_vector_type(8)));
typedef float floatx4 __attribute__((ext_vector_type(4)));

// s_waitcnt immediates (gfx9 encoding): vmcnt[3:0] @0, expcnt @4, lgkmcnt @8
#define WAIT_VM0 0x0F70   // vmcnt(0), lgkmcnt/expcnt = no-wait

// ---- workspace layout (bytes) ----
#define WS_XB    0ull           // x bf16            [4096*1024]   8.4 MB
#define WS_W1T   8388608ull     // W1^T bf16         [8][4096][1024] 67.1 MB
#define WS_W2T   75497472ull    // W2^T bf16         [8][1024][4096] 67.1 MB
#define WS_H     142606336ull   // h bf16            [8192][4096]  67.1 MB
#define WS_META  209715200ull
// meta region offsets
#define MO_CNT    0     // int[8]
#define MO_OFF    64    // int[8]
#define MO_TILE_E 128   // int[96]
#define MO_TILE_S 512   // int[96]
#define MO_TILE_R 896   // int[96]
#define MO_NT     1280  // int[1]
#define MO_CURG   1344  // int[8]
#define MO_T2I    1536  // int[4096*2]
#define MO_T2W    34304 // float[4096*2]
#define MO_ROWS   67072 // int[8192]
#define MO_ROWW   99840 // float[8192]

// async global->LDS, 16 B per lane; LDS dest = wave-uniform base + lane*16
__device__ __forceinline__ void gload16(const bf16* g, bf16* l) {
  __builtin_amdgcn_global_load_lds(
      (const __attribute__((address_space(1))) void*)g,
      (__attribute__((address_space(3))) void*)l, 16, 0, 0);
}

// ---------------- cast x: fp32 -> bf16 ----------------
__global__ void k_cast_x(const float* __restrict__ in, bf16* __restrict__ out) {
  int i = (blockIdx.x * 256 + threadIdx.x) * 8;
  float4 a = *(const float4*)(in + i);
  float4 b = *(const float4*)(in + i + 4);
  union { int4 v; bf16 h[8]; } u;
  u.h[0] = __float2bfloat16(a.x); u.h[1] = __float2bfloat16(a.y);
  u.h[2] = __float2bfloat16(a.z); u.h[3] = __float2bfloat16(a.w);
  u.h[4] = __float2bfloat16(b.x); u.h[5] = __float2bfloat16(b.y);
  u.h[6] = __float2bfloat16(b.z); u.h[7] = __float2bfloat16(b.w);
  *(int4*)(out + i) = u.v;
}

// ------- transpose+cast: [R][C] fp32 -> [C][R] bf16, per expert (z) -------
// 64x64 tile, 256 threads. LDS t[c][r] stride 65 (odd -> 2-way alias, free).
__global__ void k_transpose_cast(const float* __restrict__ in, bf16* __restrict__ out,
                                 int R, int C) {
  __shared__ float t[64][65];
  size_t ebase = (size_t)blockIdx.z * R * C;
  int c0 = blockIdx.x * 64, r0 = blockIdx.y * 64;
  int tid = threadIdx.x;
  int rr = tid >> 4;            // 0..15
  int cq = (tid & 15) * 4;      // 0,4,...,60
  #pragma unroll
  for (int i = 0; i < 4; i++) {
    int r = rr + i * 16;
    float4 v = *(const float4*)(in + ebase + (size_t)(r0 + r) * C + c0 + cq);
    t[cq + 0][r] = v.x; t[cq + 1][r] = v.y; t[cq + 2][r] = v.z; t[cq + 3][r] = v.w;
  }
  __syncthreads();
  int cc = tid >> 3;            // 0..31
  int rq = (tid & 7) * 8;       // 0,8,...,56
  #pragma unroll
  for (int i = 0; i < 2; i++) {
    int c = cc + i * 32;
    union { int4 v; bf16 h[8]; } u;
    #pragma unroll
    for (int j = 0; j < 8; j++) u.h[j] = __float2bfloat16(t[c][rq + j]);
    *(int4*)(out + ebase + (size_t)(c0 + c) * R + r0 + rq) = u.v;
  }
}

// ---------------- gating: softmax -> top2 -> softmax(top2 probs) ----------------
__global__ void k_gate(const float* __restrict__ x, const float* __restrict__ Wg,
                       const float* __restrict__ bg, int* __restrict__ t2i,
                       float* __restrict__ t2w, int* __restrict__ cnt) {
  int wave = threadIdx.x >> 6, lane = threadIdx.x & 63;
  int t = blockIdx.x * 4 + wave;
  const float* xr = x + (size_t)t * DIN;
  float acc[8] = {0.f, 0.f, 0.f, 0.f, 0.f, 0.f, 0.f, 0.f};
  for (int d = lane; d < DIN; d += 64) {
    float xv = xr[d];
    const float* wr = Wg + d * 8;
    float4 w0 = *(const float4*)wr;
    float4 w1 = *(const float4*)(wr + 4);
    acc[0] += xv * w0.x; acc[1] += xv * w0.y; acc[2] += xv * w0.z; acc[3] += xv * w0.w;
    acc[4] += xv * w1.x; acc[5] += xv * w1.y; acc[6] += xv * w1.z; acc[7] += xv * w1.w;
  }
  #pragma unroll
  for (int off = 32; off; off >>= 1) {
    #pragma unroll
    for (int e = 0; e < 8; e++) acc[e] += __shfl_xor(acc[e], off, 64);
  }
  if (lane == 0) {
    float p[8], m = -1e30f, s = 0.f;
    #pragma unroll
    for (int e = 0; e < 8; e++) { p[e] = acc[e] + bg[e]; m = fmaxf(m, p[e]); }
    #pragma unroll
    for (int e = 0; e < 8; e++) { p[e] = expf(p[e] - m); s += p[e]; }
    float inv = 1.f / s;
    #pragma unroll
    for (int e = 0; e < 8; e++) p[e] *= inv;
    int i0 = 0;
    #pragma unroll
    for (int e = 1; e < 8; e++) if (p[e] > p[i0]) i0 = e;   // ties -> lowest idx
    int i1 = (i0 == 0) ? 1 : 0;
    #pragma unroll
    for (int e = 0; e < 8; e++) if (e != i0 && p[e] > p[i1]) i1 = e;
    float d = expf(p[i1] - p[i0]);           // softmax over the two PROBABILITIES
    float w0 = 1.f / (1.f + d), w1 = d / (1.f + d);
    t2i[2 * t] = i0; t2i[2 * t + 1] = i1;
    t2w[2 * t] = w0; t2w[2 * t + 1] = w1;
    atomicAdd(&cnt[i0], 1);
    atomicAdd(&cnt[i1], 1);
  }
}

// ---------------- routing metadata: offsets + tile map (trivial, 8 experts) ----
__global__ void k_meta(const int* __restrict__ cnt, int* __restrict__ off,
                       int* __restrict__ tile_e, int* __restrict__ tile_s,
                       int* __restrict__ tile_r, int* __restrict__ nt,
                       int* __restrict__ cur_g) {
  if (threadIdx.x == 0) {
    int o = 0, n = 0;
    for (int e = 0; e < 8; e++) {
      off[e] = o; cur_g[e] = o;
      int c = cnt[e];
      for (int r = 0; r < c; r += 128) {
        tile_e[n] = e; tile_s[n] = o + r; tile_r[n] = min(128, c - r); n++;
      }
      o += c;
    }
    *nt = n;
  }
}

// ---------------- scatter: two-level (LDS rank, one global atomic per blk*exp) ----
__global__ void k_scatter(const int* __restrict__ t2i, const float* __restrict__ t2w,
                          int* __restrict__ cur_g, int* __restrict__ rows,
                          float* __restrict__ roww) {
  __shared__ int lcnt[8], lbase[8];
  if (threadIdx.x < 8) lcnt[threadIdx.x] = 0;
  __syncthreads();
  int t = blockIdx.x * 256 + threadIdx.x;
  int e0 = t2i[2 * t], e1 = t2i[2 * t + 1];
  int p0 = atomicAdd(&lcnt[e0], 1);
  int p1 = atomicAdd(&lcnt[e1], 1);
  __syncthreads();
  if (threadIdx.x < 8)
    lbase[threadIdx.x] = atomicAdd(&cur_g[threadIdx.x], lcnt[threadIdx.x]);
  __syncthreads();
  int a0 = lbase[e0] + p0, a1 = lbase[e1] + p1;
  rows[a0] = t; roww[a0] = t2w[2 * t];
  rows[a1] = t; roww[a1] = t2w[2 * t + 1];
}

// ---- grouped GEMM, 128x128 tile, BK=32, 4 waves, pipelined async staging ----
// Double-buffered LDS, ONE raw barrier per K-iter, manual vmcnt — loads for
// tile k+1 stay in flight across iter k's MFMA section (AITER-style).
// MODE 1: h = relu(x_gathered @ W1T^T + b1), bf16 out
// MODE 2: out[token] += w * (h @ W2T^T + b2), fp32 atomic
template <int MODE>
__global__ __launch_bounds__(256)
void k_gemm(const bf16* __restrict__ A, const bf16* __restrict__ Bt,
            const float* __restrict__ bias,
            const int* __restrict__ tile_e, const int* __restrict__ tile_s,
            const int* __restrict__ tile_r, const int* __restrict__ nt,
            const int* __restrict__ rows, const float* __restrict__ roww,
            bf16* __restrict__ hout, float* __restrict__ out,
            int K, int N) {
  int tile = blockIdx.x;
  if (tile >= *nt) return;
  int e = tile_e[tile], start = tile_s[tile], mrows = tile_r[tile];
  int n0 = blockIdx.y * 128;
  int tid = threadIdx.x, lane = tid & 63, wave = tid >> 6;
  int wm = wave & 1, wn = wave >> 1;

  // unpadded [128][32] bf16 tiles, double-buffered (8 KB x 4 = 32 KB)
  __shared__ bf16 Al[2][128 * 32];
  __shared__ bf16 Bl[2][128 * 32];

  int srow = tid >> 2;          // 0..63
  int kc8  = (tid & 3) * 8;     // k elem offset
  int ra0 = srow, ra1 = 64 + srow;
  int er0 = ra0 < mrows ? ra0 : 0;
  int er1 = ra1 < mrows ? ra1 : 0;
  size_t ga0, ga1;
  if (MODE == 1) {
    ga0 = (size_t)rows[start + er0] * K;
    ga1 = (size_t)rows[start + er1] * K;
  } else {
    ga0 = (size_t)(start + er0) * K;
    ga1 = (size_t)(start + er1) * K;
  }
  const bf16* ap0 = A + ga0 + kc8;
  const bf16* ap1 = A + ga1 + kc8;
  const bf16* bb = Bt + (size_t)e * K * N + (size_t)n0 * K;
  const bf16* bp0 = bb + (size_t)srow * K + kc8;
  const bf16* bp1 = bb + (size_t)(64 + srow) * K + kc8;

  floatx4 zz = {0.f, 0.f, 0.f, 0.f};
  floatx4 acc[4][4];
  #pragma unroll
  for (int i = 0; i < 4; i++)
    #pragma unroll
    for (int j = 0; j < 4; j++) acc[i][j] = zz;

  int fr = lane & 15, ko = (lane >> 4) * 8;

  // prologue: issue tile 0 into buffer 0
  gload16(ap0, &Al[0][tid * 8]);
  gload16(ap1, &Al[0][2048 + tid * 8]);
  gload16(bp0, &Bl[0][tid * 8]);
  gload16(bp1, &Bl[0][2048 + tid * 8]);

  int cur = 0;
  for (int k0 = 0; k0 < K; k0 += 32) {
    // drain current tile's 4 loads (the only outstanding vmem), then barrier.
    // Raw s_barrier: no compiler-inserted full drain.
    __builtin_amdgcn_s_waitcnt(WAIT_VM0);
    __builtin_amdgcn_s_barrier();

    // read fragments of current tile first (any conservative wait sees 0
    // outstanding vmem here)
    short8 af[4], bfr[4];
    #pragma unroll
    for (int i = 0; i < 4; i++)
      af[i] = *(const short8*)&Al[cur][(wm * 64 + i * 16 + fr) * 32 + ko];
    #pragma unroll
    for (int j = 0; j < 4; j++)
      bfr[j] = *(const short8*)&Bl[cur][(wn * 64 + j * 16 + fr) * 32 + ko];

    // issue next tile into the other buffer; stays in flight across MFMAs
    // (safe: everyone's reads of buf cur^1 finished before this barrier)
    int nxt = cur ^ 1;
    if (k0 + 32 < K) {
      gload16(ap0 + k0 + 32, &Al[nxt][tid * 8]);
      gload16(ap1 + k0 + 32, &Al[nxt][2048 + tid * 8]);
      gload16(bp0 + k0 + 32, &Bl[nxt][tid * 8]);
      gload16(bp1 + k0 + 32, &Bl[nxt][2048 + tid * 8]);
    }

    #pragma unroll
    for (int i = 0; i < 4; i++)
      #pragma unroll
      for (int j = 0; j < 4; j++)
        acc[i][j] = __builtin_amdgcn_mfma_f32_16x16x32_bf16(af[i], bfr[j], acc[i][j], 0, 0, 0);
    cur = nxt;
  }

  // epilogue: C/D layout col=lane&15, row=(lane>>4)*4+reg
  int col_l = lane & 15, quad = lane >> 4;
  if (MODE == 1) {
    #pragma unroll
    for (int i = 0; i < 4; i++) {
      #pragma unroll
      for (int r = 0; r < 4; r++) {
        int row = wm * 64 + i * 16 + quad * 4 + r;
        if (row < mrows) {
          size_t rb = (size_t)(start + row) * N;
          #pragma unroll
          for (int j = 0; j < 4; j++) {
            int col = n0 + wn * 64 + j * 16 + col_l;
            float v = acc[i][j][r] + bias[e * N + col];
            hout[rb + col] = __float2bfloat16(fmaxf(v, 0.f));
          }
        }
      }
    }
  } else {
    #pragma unroll
    for (int i = 0; i < 4; i++) {
      #pragma unroll
      for (int r = 0; r < 4; r++) {
        int row = wm * 64 + i * 16 + quad * 4 + r;
        if (row < mrows) {
          int tok = rows[start + row];
          float w = roww[start + row];
          size_t ob = (size_t)tok * N;
          #pragma unroll
          for (int j = 0; j < 4; j++) {
            int col = n0 + wn * 64 + j * 16 + col_l;
            float v = (acc[i][j][r] + bias[e * N + col]) * w;
            unsafeAtomicAdd(&out[ob + col], v);
          }
        }
      }
    }
  }
}

extern "C" void kernel_launch(void* const* d_in, const int* in_sizes, int n_in,
                              void* d_out, int out_size, void* d_ws, size_t ws_size,
                              hipStream_t stream) {
  const float* x  = (const float*)d_in[0];
  const float* W1 = (const float*)d_in[1];
  const float* b1 = (const float*)d_in[2];
  const float* W2 = (const float*)d_in[3];
  const float* b2 = (const float*)d_in[4];
  const float* Wg = (const float*)d_in[5];
  const float* bg = (const float*)d_in[6];
  float* out = (float*)d_out;
  char* ws = (char*)d_ws;

  bf16* xb  = (bf16*)(ws + WS_XB);
  bf16* w1t = (bf16*)(ws + WS_W1T);
  bf16* w2t = (bf16*)(ws + WS_W2T);
  bf16* h   = (bf16*)(ws + WS_H);
  char* meta = ws + WS_META;
  int*   cnt    = (int*)(meta + MO_CNT);
  int*   off    = (int*)(meta + MO_OFF);
  int*   tile_e = (int*)(meta + MO_TILE_E);
  int*   tile_s = (int*)(meta + MO_TILE_S);
  int*   tile_r = (int*)(meta + MO_TILE_R);
  int*   nt     = (int*)(meta + MO_NT);
  int*   cur_g  = (int*)(meta + MO_CURG);
  int*   t2i    = (int*)(meta + MO_T2I);
  float* t2w    = (float*)(meta + MO_T2W);
  int*   rows   = (int*)(meta + MO_ROWS);
  float* roww   = (float*)(meta + MO_ROWW);

  hipMemsetAsync(cnt, 0, 64, stream);
  hipMemsetAsync(d_out, 0, (size_t)out_size * sizeof(float), stream);

  k_cast_x<<<(NTOK * DIN) / (256 * 8), 256, 0, stream>>>(x, xb);
  k_transpose_cast<<<dim3(DHID / 64, DIN / 64, NEXP), 256, 0, stream>>>(W1, w1t, DIN, DHID);
  k_transpose_cast<<<dim3(DOUT / 64, DHID / 64, NEXP), 256, 0, stream>>>(W2, w2t, DHID, DOUT);
  k_gate<<<NTOK / 4, 256, 0, stream>>>(x, Wg, bg, t2i, t2w, cnt);
  k_meta<<<1, 64, 0, stream>>>(cnt, off, tile_e, tile_s, tile_r, nt, cur_g);
  k_scatter<<<NTOK / 256, 256, 0, stream>>>(t2i, t2w, cur_g, rows, roww);
  k_gemm<1><<<dim3(TMAX, DHID / 128), 256, 0, stream>>>(
      xb, w1t, b1, tile_e, tile_s, tile_r, nt, rows, roww, h, nullptr, DIN, DHID);
  k_gemm<2><<<dim3(TMAX, DOUT / 128), 256, 0, stream>>>(
      h, w2t, b2, tile_e, tile_s, tile_r, nt, rows, roww, nullptr, out, DHID, DOUT);
}